// Round 11
// baseline (203.184 us; speedup 1.0000x reference)
//
#include <hip/hip_runtime.h>

typedef __bf16 bf16x8 __attribute__((ext_vector_type(8)));
typedef float f32x4 __attribute__((ext_vector_type(4)));
typedef float f32x16 __attribute__((ext_vector_type(16)));
typedef unsigned short ushort8 __attribute__((ext_vector_type(8)));
typedef unsigned int uint4v __attribute__((ext_vector_type(4)));

__device__ __forceinline__ unsigned short f2bf(float f) {
  __bf16 b = (__bf16)f;
  return __builtin_bit_cast(unsigned short, b);
}
__device__ __forceinline__ float bf2f(unsigned short u) {
  unsigned int x = ((unsigned int)u) << 16;
  return __builtin_bit_cast(float, x);
}

// async global->LDS, 16B per lane; LDS dest must be wave-uniform base + lane*16
#define GLOAD_LDS16(g, l)                                              \
  __builtin_amdgcn_global_load_lds(                                    \
      (const __attribute__((address_space(1))) void*)(g),              \
      (__attribute__((address_space(3))) void*)(l), 16, 0, 0)

// ---------------- x f32 -> bf16 ----------------
__global__ __launch_bounds__(256) void f32_to_bf16_kernel(const float* __restrict__ in,
                                                          __bf16* __restrict__ out) {
  int i = blockIdx.x * 256 + threadIdx.x;
  const float4* p = (const float4*)(in + (size_t)i * 8);
  float4 f0 = p[0], f1 = p[1];
  ushort8 u = {f2bf(f0.x), f2bf(f0.y), f2bf(f0.z), f2bf(f0.w),
               f2bf(f1.x), f2bf(f1.y), f2bf(f1.z), f2bf(f1.w)};
  *(ushort8*)((unsigned short*)out + (size_t)i * 8) = u;
}

// ---------------- W transpose + f32->bf16 convert: Wt[n][k] = W[k][n] ----------------
__global__ __launch_bounds__(256) void wtrans_kernel(const float* __restrict__ W,
                                                     __bf16* __restrict__ Wt,
                                                     int K, int N) {
  __shared__ float tile[32][33];
  int tx = threadIdx.x, ty = threadIdx.y;  // block (32,8)
  int n0 = blockIdx.x * 32, k0 = blockIdx.y * 32;
#pragma unroll
  for (int i = 0; i < 32; i += 8)
    tile[ty + i][tx] = W[(size_t)(k0 + ty + i) * N + n0 + tx];
  __syncthreads();
#pragma unroll
  for (int i = 0; i < 32; i += 8)
    Wt[(size_t)(n0 + ty + i) * K + k0 + tx] = (__bf16)tile[tx][ty + i];
}

// ---------------- GEMM 256x128x64, counted-vmcnt (r9 proven: 88.0 us) ----------------
template <int OUT_F32, int KSPLIT>
__global__ __launch_bounds__(512, 2) void gemm256_kernel(const __bf16* __restrict__ Ab,
                                                         const __bf16* __restrict__ Bt,
                                                         const float* __restrict__ bias,
                                                         void* __restrict__ Cp,
                                                         __bf16* __restrict__ Kbp,
                                                         int M, int N, int K) {
  __shared__ __align__(16) unsigned short As[2][256 * 64];
  __shared__ __align__(16) unsigned short Bs[2][128 * 64];
  const int tid = threadIdx.x;
  const int lane = tid & 63;
  const int wid = tid >> 6;
  const int lr = lane & 15, lg = lane >> 4;
  const int wr = wid >> 1, wc = wid & 1;
  const int gx = gridDim.x;
  int nwg = gx * gridDim.y;
  int bid = blockIdx.y * gx + blockIdx.x;
  if ((nwg & 7) == 0) {
    int cpx = nwg >> 3;
    bid = (bid & 7) * cpx + (bid >> 3);
  }
  const int m0 = (bid / gx) * 256, n0 = (bid % gx) * 128;
  const int srow = tid >> 3;
  const int scol = ((tid & 7) ^ (srow & 7)) * 8;
  const unsigned short* Ag = (const unsigned short*)Ab + (size_t)(m0 + srow) * K + scol;
  const unsigned short* Bg = (const unsigned short*)Bt + (size_t)(n0 + srow) * K + scol;

#define STAGE256(t, bi)                                                      \
  {                                                                          \
    const int _k0 = (t) * 64;                                                \
    GLOAD_LDS16(Ag + _k0, &As[bi][tid * 8]);                                 \
    GLOAD_LDS16(Ag + (size_t)64 * K + _k0, &As[bi][4096 + tid * 8]);         \
    GLOAD_LDS16(Ag + (size_t)128 * K + _k0, &As[bi][8192 + tid * 8]);        \
    GLOAD_LDS16(Ag + (size_t)192 * K + _k0, &As[bi][12288 + tid * 8]);       \
    GLOAD_LDS16(Bg + _k0, &Bs[bi][tid * 8]);                                 \
    GLOAD_LDS16(Bg + (size_t)64 * K + _k0, &Bs[bi][4096 + tid * 8]);         \
  }

  f32x4 acc[4][4] = {};
  const int nst = K >> 6;
  STAGE256(0, 0);
  STAGE256(1, 1);
  int aoff[4][2], boff[4][2];
#pragma unroll
  for (int t = 0; t < 4; ++t)
#pragma unroll
    for (int ks = 0; ks < 2; ++ks) {
      int slot = ((ks * 4 + lg) ^ (lr & 7));
      aoff[t][ks] = (wr * 64 + t * 16 + lr) * 64 + slot * 8;
      boff[t][ks] = (wc * 64 + t * 16 + lr) * 64 + slot * 8;
    }

  for (int i = 0; i < nst; ++i) {
    const int cur = i & 1;
    if (i + 1 < nst)
      asm volatile("s_waitcnt vmcnt(6)" ::: "memory");
    else
      asm volatile("s_waitcnt vmcnt(0)" ::: "memory");
    asm volatile("s_barrier" ::: "memory");
    const unsigned short* Ac = &As[cur][0];
    const unsigned short* Bc = &Bs[cur][0];
    bf16x8 af[4][2], bq[4][2];
#pragma unroll
    for (int t = 0; t < 4; ++t)
#pragma unroll
      for (int ks = 0; ks < 2; ++ks) {
        af[t][ks] = *(const bf16x8*)&Ac[aoff[t][ks]];
        bq[t][ks] = *(const bf16x8*)&Bc[boff[t][ks]];
      }
    asm volatile("s_waitcnt lgkmcnt(0)" ::: "memory");
    asm volatile("s_barrier" ::: "memory");
    if (i + 2 < nst) STAGE256(i + 2, cur);
    __builtin_amdgcn_s_setprio(1);
#pragma unroll
    for (int mt = 0; mt < 4; ++mt)
#pragma unroll
      for (int nt = 0; nt < 4; ++nt)
#pragma unroll
        for (int ks = 0; ks < 2; ++ks)
          acc[mt][nt] =
              __builtin_amdgcn_mfma_f32_16x16x32_bf16(af[mt][ks], bq[nt][ks], acc[mt][nt], 0, 0, 0);
    __builtin_amdgcn_s_setprio(0);
  }
#undef STAGE256

  const bool isK = KSPLIT && (n0 >= 1024) && (n0 < 2048);
#pragma unroll
  for (int mt = 0; mt < 4; ++mt)
#pragma unroll
    for (int nt = 0; nt < 4; ++nt)
#pragma unroll
      for (int jj = 0; jj < 4; ++jj) {
        int row = m0 + wr * 64 + mt * 16 + lg * 4 + jj;
        int col = n0 + wc * 64 + nt * 16 + lr;
        float v = acc[mt][nt][jj] + bias[col];
        if (OUT_F32) {
          ((float*)Cp)[(size_t)row * N + col] = v;
        } else if (isK) {
          int h = (col - 1024) >> 6, d = col & 63;
          int bq2 = row >> 11, t = row & 2047;
          ((unsigned short*)Kbp)[(size_t)((bq2 * 16 + h) * 2048 + t) * 64 + d] = f2bf(v);
        } else {
          ((unsigned short*)Cp)[(size_t)row * N + col] = f2bf(v);
        }
      }
}

// ---------------- qkv(v part) -> Vt [B,H,D,T] (tiled transpose) ----------------
__global__ __launch_bounds__(256) void vtrans_kernel(const __bf16* __restrict__ qkv,
                                                     __bf16* __restrict__ Vt) {
  __shared__ __align__(16) unsigned short tile[64][72];
  int bh = blockIdx.y, b = bh >> 4, h = bh & 15;
  int t0 = blockIdx.x * 64;
  int tid = threadIdx.x;
#pragma unroll
  for (int p = 0; p < 2; ++p) {
    int idx = p * 256 + tid;
    int r = idx >> 3, c8 = (idx & 7) * 8;
    *(ushort8*)&tile[r][c8] = *(const ushort8*)((const unsigned short*)qkv +
                                                (size_t)(b * 2048 + t0 + r) * 3072 + 2048 +
                                                h * 64 + c8);
  }
  __syncthreads();
#pragma unroll
  for (int p = 0; p < 2; ++p) {
    int idx = p * 256 + tid;
    int d = idx >> 3, c8 = (idx & 7) * 8;
    ushort8 u;
#pragma unroll
    for (int i = 0; i < 8; ++i) u[i] = tile[c8 + i][d];
    *(ushort8*)((unsigned short*)Vt + (size_t)(bh * 64 + d) * 2048 + t0 + c8) = u;
  }
}

// ---------------- flash attention (causal), PAIRED q-blocks over shared KV ----------------
// QBLK=128, 4 waves x 32 q-rows. Block handles q-blocks (p, 15-p): uniform
// (2p+2)+(2(15-p)+2) = 36 tile-computes per block -> perfect load balance.
// KV staging shared (B's range covers A's). Double-buffered LDS, 1 barrier/iter.
__global__ __launch_bounds__(256) void attn_kernel(const __bf16* __restrict__ qkvp,
                                                   const __bf16* __restrict__ Kg,
                                                   const __bf16* __restrict__ Vt,
                                                   __bf16* __restrict__ yb) {
  __shared__ __align__(16) unsigned short Ks[2][64][72];
  __shared__ __align__(16) unsigned short Vs[2][64][72];
  const int bx = blockIdx.x;
  const int p = bx >> 6;       // 0..7
  const int bh = bx & 63;
  const int qbA = p, qbB = 15 - p;
  const int b = bh >> 4, h = bh & 15;
  const int tid = threadIdx.x, wid = tid >> 6, lane = tid & 63;
  const int lq = lane & 31, hi = lane >> 5;
  const unsigned short* qkv = (const unsigned short*)qkvp;
  const unsigned short* Kh = (const unsigned short*)Kg + (size_t)bh * 2048 * 64;
  const unsigned short* Vh = (const unsigned short*)Vt + (size_t)bh * 64 * 2048;
  const int q0A = qbA * 128 + wid * 32, q0B = qbB * 128 + wid * 32;
  const int jmaxA = 2 * qbA + (wid >> 1), jmaxB = 2 * qbB + (wid >> 1);
  const int qrel = (wid & 1) * 32 + lq;
  const int J = 2 * qbB + 2;

  const float qs = 0.125f * 1.44269504f;
  bf16x8 qfA[4], qfB[4];
  auto loadq = [&](int q0, bf16x8* qf) {
    const unsigned short* Qg = qkv + (size_t)(b * 2048 + q0 + lq) * 3072 + h * 64;
#pragma unroll
    for (int dc = 0; dc < 4; ++dc) {
      ushort8 uq = *(const ushort8*)(Qg + dc * 16 + hi * 8);
      uint4v w;
#pragma unroll
      for (int i = 0; i < 4; ++i) {
        float lo = bf2f(uq[2 * i]) * qs;
        float hh = bf2f(uq[2 * i + 1]) * qs;
        unsigned int up;
        asm("v_cvt_pk_bf16_f32 %0, %1, %2" : "=v"(up) : "v"(lo), "v"(hh));
        w[i] = up;
      }
      qf[dc] = __builtin_bit_cast(bf16x8, w);
    }
  };
  loadq(q0A, qfA);
  loadq(q0B, qfB);

  f32x16 yaccA[2] = {}, yaccB[2] = {};
  float mA = -1e30f, lA = 0.f, mB = -1e30f, lB = 0.f;

  // per-KV-tile compute for one q-block state
  auto compute = [&](int j, int cb, int jmax, const bf16x8* qf, f32x16* yacc, float& m_r,
                     float& l_r) {
    f32x16 sa[2];
#pragma unroll
    for (int kt32 = 0; kt32 < 2; ++kt32) {
      f32x16 s = {};
#pragma unroll
      for (int dc = 0; dc < 4; ++dc) {
        bf16x8 kf = *(const bf16x8*)&Ks[cb][kt32 * 32 + lq][dc * 16 + hi * 8];
        s = __builtin_amdgcn_mfma_f32_32x32x16_bf16(kf, qf[dc], s, 0, 0, 0);
      }
      sa[kt32] = s;
    }
    if (j == jmax) {
#pragma unroll
      for (int kt32 = 0; kt32 < 2; ++kt32)
#pragma unroll
        for (int reg = 0; reg < 16; ++reg) {
          int kl = kt32 * 32 + (reg & 3) + 8 * (reg >> 2) + 4 * hi;
          if (kl > qrel) sa[kt32][reg] = -1e30f;
        }
    }
    float pmax = -1e30f;
#pragma unroll
    for (int kt32 = 0; kt32 < 2; ++kt32)
#pragma unroll
      for (int reg = 0; reg < 16; reg += 4)
        pmax = fmaxf(pmax, fmaxf(fmaxf(sa[kt32][reg], sa[kt32][reg + 1]),
                                 fmaxf(sa[kt32][reg + 2], sa[kt32][reg + 3])));
    pmax = fmaxf(pmax, __shfl_xor(pmax, 32));
    const bool need = __any(pmax > m_r + 8.f) != 0;
    const float mnew = need ? fmaxf(m_r, pmax) : m_r;
    const float alpha = exp2f(m_r - mnew);
    unsigned int u[2][8];
    float rs = 0.f;
#pragma unroll
    for (int kt32 = 0; kt32 < 2; ++kt32)
#pragma unroll
      for (int rr = 0; rr < 8; ++rr) {
        float p0 = exp2f(sa[kt32][2 * rr] - mnew);
        float p1 = exp2f(sa[kt32][2 * rr + 1] - mnew);
        rs += p0 + p1;
        unsigned int up;
        asm("v_cvt_pk_bf16_f32 %0, %1, %2" : "=v"(up) : "v"(p0), "v"(p1));
        u[kt32][rr] = up;
      }
    rs += __shfl_xor(rs, 32);
    l_r = l_r * alpha + rs;
    m_r = mnew;
    if (need) {
#pragma unroll
      for (int reg = 0; reg < 16; ++reg) {
        int row = (reg & 3) + 8 * (reg >> 2) + 4 * hi;
        float ac = __shfl(alpha, row);
        yacc[0][reg] *= ac;
        yacc[1][reg] *= ac;
      }
    }
#pragma unroll
    for (int kt = 0; kt < 4; ++kt) {
      const int kt32 = kt >> 1, off = 4 * (kt & 1);
      unsigned int a0 = u[kt32][off + 0], a2 = u[kt32][off + 2];
      unsigned int a1 = u[kt32][off + 1], a3 = u[kt32][off + 3];
      asm("v_permlane32_swap_b32 %0, %1" : "+v"(a0), "+v"(a2));
      asm("v_permlane32_swap_b32 %0, %1" : "+v"(a1), "+v"(a3));
      uint4v pav = {a0, a1, a2, a3};
      bf16x8 paf = __builtin_bit_cast(bf16x8, pav);
#pragma unroll
      for (int dt = 0; dt < 2; ++dt) {
        bf16x8 vf = *(const bf16x8*)&Vs[cb][dt * 32 + lq][kt * 16 + hi * 8];
        yacc[dt] = __builtin_amdgcn_mfma_f32_32x32x16_bf16(paf, vf, yacc[dt], 0, 0, 0);
      }
    }
  };

  // prologue: stage tile 0 into buffer 0 (256 thr: 2 passes cover 64 rows)
#pragma unroll
  for (int pp = 0; pp < 2; ++pp) {
    int idx = pp * 256 + tid;
    int r = idx >> 3, c8 = (idx & 7) * 8;
    *(ushort8*)&Ks[0][r][c8] = *(const ushort8*)(Kh + (size_t)r * 64 + c8);
    *(ushort8*)&Vs[0][r][c8] = *(const ushort8*)(Vh + (size_t)r * 2048 + c8);
  }

  for (int j = 0; j < J; ++j) {
    __syncthreads();
    if (j + 1 < J) {
      int bi = (j + 1) & 1;
#pragma unroll
      for (int pp = 0; pp < 2; ++pp) {
        int idx = pp * 256 + tid;
        int r = idx >> 3, c8 = (idx & 7) * 8;
        *(ushort8*)&Ks[bi][r][c8] =
            *(const ushort8*)(Kh + (size_t)((j + 1) * 64 + r) * 64 + c8);
        *(ushort8*)&Vs[bi][r][c8] =
            *(const ushort8*)(Vh + (size_t)r * 2048 + (j + 1) * 64 + c8);
      }
    }
    const int cb = j & 1;
    if (j <= jmaxA) compute(j, cb, jmaxA, qfA, yaccA, mA, lA);
    if (j <= jmaxB) compute(j, cb, jmaxB, qfB, yaccB, mB, lB);
  }

  // epilogue: both q-blocks
#pragma unroll
  for (int reg = 0; reg < 16; ++reg) {
    int row = (reg & 3) + 8 * (reg >> 2) + 4 * hi;
    float linvA = 1.f / __shfl(lA, row);
    float linvB = 1.f / __shfl(lB, row);
    int qgA = q0A + row, qgB = q0B + row;
#pragma unroll
    for (int dt = 0; dt < 2; ++dt) {
      float vA = yaccA[dt][reg] * linvA;
      float vB = yaccB[dt][reg] * linvB;
      ((unsigned short*)yb)[(size_t)(b * 2048 + qgA) * 1024 + h * 64 + dt * 32 + lq] = f2bf(vA);
      ((unsigned short*)yb)[(size_t)(b * 2048 + qgB) * 1024 + h * 64 + dt * 32 + lq] = f2bf(vB);
    }
  }
}

extern "C" void kernel_launch(void* const* d_in, const int* in_sizes, int n_in,
                              void* d_out, int out_size, void* d_ws, size_t ws_size,
                              hipStream_t stream) {
  const float* x = (const float*)d_in[0];
  const float* W_attn = (const float*)d_in[1];
  const float* b_attn = (const float*)d_in[2];
  const float* W_proj = (const float*)d_in[3];
  const float* b_proj = (const float*)d_in[4];
  float* out = (float*)d_out;
  char* ws = (char*)d_ws;

  size_t off = 0;
  __bf16* WtA = (__bf16*)(ws + off); off += (size_t)3072 * 1024 * 2;
  __bf16* WtP = (__bf16*)(ws + off); off += (size_t)1024 * 1024 * 2;
  __bf16* qkv = (__bf16*)(ws + off); off += (size_t)8192 * 3072 * 2;
  __bf16* Kb  = (__bf16*)(ws + off); off += (size_t)64 * 2048 * 64 * 2;
  __bf16* Vtb = (__bf16*)(ws + off); off += (size_t)64 * 2048 * 64 * 2;
  // xb (x in bf16) dead after GEMM1; yb written only after attn -> alias
  __bf16* xyb = (__bf16*)(ws + off); off += (size_t)8192 * 1024 * 2;
  __bf16* xb = xyb;
  __bf16* yb = xyb;
  (void)ws_size; (void)in_sizes; (void)n_in; (void)out_size;

  f32_to_bf16_kernel<<<4096, 256, 0, stream>>>(x, xb);
  wtrans_kernel<<<dim3(3072 / 32, 1024 / 32), dim3(32, 8), 0, stream>>>(W_attn, WtA, 1024, 3072);
  wtrans_kernel<<<dim3(1024 / 32, 1024 / 32), dim3(32, 8), 0, stream>>>(W_proj, WtP, 1024, 1024);
  // qkv GEMM (r9 256x128 counted-vmcnt); k columns redirected to Kb
  gemm256_kernel<0, 1><<<dim3(24, 32), 512, 0, stream>>>(xb, WtA, b_attn, qkv, Kb, 8192, 3072, 1024);
  vtrans_kernel<<<dim3(32, 64), 256, 0, stream>>>(qkv, Vtb);
  // paired attention: 512 blocks x 256 thr, uniform 36 tile-computes/block
  attn_kernel<<<dim3(512), 256, 0, stream>>>(qkv, Kb, Vtb, yb);
  // proj GEMM: 256 blocks = 1/CU
  gemm256_kernel<1, 0><<<dim3(8, 32), 512, 0, stream>>>(yb, WtP, b_proj, out, nullptr, 8192, 1024, 1024);
}

// Round 12
// 189.933 us; speedup vs baseline: 1.0698x; 1.0698x over previous
//
#include <hip/hip_runtime.h>

typedef __bf16 bf16x8 __attribute__((ext_vector_type(8)));
typedef float f32x4 __attribute__((ext_vector_type(4)));
typedef float f32x16 __attribute__((ext_vector_type(16)));
typedef unsigned short ushort8 __attribute__((ext_vector_type(8)));
typedef unsigned int uint4v __attribute__((ext_vector_type(4)));

__device__ __forceinline__ unsigned short f2bf(float f) {
  __bf16 b = (__bf16)f;
  return __builtin_bit_cast(unsigned short, b);
}
__device__ __forceinline__ float bf2f(unsigned short u) {
  unsigned int x = ((unsigned int)u) << 16;
  return __builtin_bit_cast(float, x);
}

// async global->LDS, 16B per lane; LDS dest must be wave-uniform base + lane*16
#define GLOAD_LDS16(g, l)                                              \
  __builtin_amdgcn_global_load_lds(                                    \
      (const __attribute__((address_space(1))) void*)(g),              \
      (__attribute__((address_space(3))) void*)(l), 16, 0, 0)

// ---------------- x f32 -> bf16 ----------------
__global__ __launch_bounds__(256) void f32_to_bf16_kernel(const float* __restrict__ in,
                                                          __bf16* __restrict__ out) {
  int i = blockIdx.x * 256 + threadIdx.x;
  const float4* p = (const float4*)(in + (size_t)i * 8);
  float4 f0 = p[0], f1 = p[1];
  ushort8 u = {f2bf(f0.x), f2bf(f0.y), f2bf(f0.z), f2bf(f0.w),
               f2bf(f1.x), f2bf(f1.y), f2bf(f1.z), f2bf(f1.w)};
  *(ushort8*)((unsigned short*)out + (size_t)i * 8) = u;
}

// ---------------- W transpose + f32->bf16 convert: Wt[n][k] = W[k][n] ----------------
__global__ __launch_bounds__(256) void wtrans_kernel(const float* __restrict__ W,
                                                     __bf16* __restrict__ Wt,
                                                     int K, int N) {
  __shared__ float tile[32][33];
  int tx = threadIdx.x, ty = threadIdx.y;  // block (32,8)
  int n0 = blockIdx.x * 32, k0 = blockIdx.y * 32;
#pragma unroll
  for (int i = 0; i < 32; i += 8)
    tile[ty + i][tx] = W[(size_t)(k0 + ty + i) * N + n0 + tx];
  __syncthreads();
#pragma unroll
  for (int i = 0; i < 32; i += 8)
    Wt[(size_t)(n0 + ty + i) * K + k0 + tx] = (__bf16)tile[tx][ty + i];
}

// ---------------- GEMM 256x128x64, counted-vmcnt (r9 proven: 88.0 us) ----------------
template <int OUT_F32, int KSPLIT>
__global__ __launch_bounds__(512, 2) void gemm256_kernel(const __bf16* __restrict__ Ab,
                                                         const __bf16* __restrict__ Bt,
                                                         const float* __restrict__ bias,
                                                         void* __restrict__ Cp,
                                                         __bf16* __restrict__ Kbp,
                                                         int M, int N, int K) {
  __shared__ __align__(16) unsigned short As[2][256 * 64];
  __shared__ __align__(16) unsigned short Bs[2][128 * 64];
  const int tid = threadIdx.x;
  const int lane = tid & 63;
  const int wid = tid >> 6;
  const int lr = lane & 15, lg = lane >> 4;
  const int wr = wid >> 1, wc = wid & 1;
  const int gx = gridDim.x;
  int nwg = gx * gridDim.y;
  int bid = blockIdx.y * gx + blockIdx.x;
  if ((nwg & 7) == 0) {
    int cpx = nwg >> 3;
    bid = (bid & 7) * cpx + (bid >> 3);
  }
  const int m0 = (bid / gx) * 256, n0 = (bid % gx) * 128;
  const int srow = tid >> 3;
  const int scol = ((tid & 7) ^ (srow & 7)) * 8;
  const unsigned short* Ag = (const unsigned short*)Ab + (size_t)(m0 + srow) * K + scol;
  const unsigned short* Bg = (const unsigned short*)Bt + (size_t)(n0 + srow) * K + scol;

#define STAGE256(t, bi)                                                      \
  {                                                                          \
    const int _k0 = (t) * 64;                                                \
    GLOAD_LDS16(Ag + _k0, &As[bi][tid * 8]);                                 \
    GLOAD_LDS16(Ag + (size_t)64 * K + _k0, &As[bi][4096 + tid * 8]);         \
    GLOAD_LDS16(Ag + (size_t)128 * K + _k0, &As[bi][8192 + tid * 8]);        \
    GLOAD_LDS16(Ag + (size_t)192 * K + _k0, &As[bi][12288 + tid * 8]);       \
    GLOAD_LDS16(Bg + _k0, &Bs[bi][tid * 8]);                                 \
    GLOAD_LDS16(Bg + (size_t)64 * K + _k0, &Bs[bi][4096 + tid * 8]);         \
  }

  f32x4 acc[4][4] = {};
  const int nst = K >> 6;
  STAGE256(0, 0);
  STAGE256(1, 1);
  int aoff[4][2], boff[4][2];
#pragma unroll
  for (int t = 0; t < 4; ++t)
#pragma unroll
    for (int ks = 0; ks < 2; ++ks) {
      int slot = ((ks * 4 + lg) ^ (lr & 7));
      aoff[t][ks] = (wr * 64 + t * 16 + lr) * 64 + slot * 8;
      boff[t][ks] = (wc * 64 + t * 16 + lr) * 64 + slot * 8;
    }

  for (int i = 0; i < nst; ++i) {
    const int cur = i & 1;
    if (i + 1 < nst)
      asm volatile("s_waitcnt vmcnt(6)" ::: "memory");
    else
      asm volatile("s_waitcnt vmcnt(0)" ::: "memory");
    asm volatile("s_barrier" ::: "memory");
    const unsigned short* Ac = &As[cur][0];
    const unsigned short* Bc = &Bs[cur][0];
    bf16x8 af[4][2], bq[4][2];
#pragma unroll
    for (int t = 0; t < 4; ++t)
#pragma unroll
      for (int ks = 0; ks < 2; ++ks) {
        af[t][ks] = *(const bf16x8*)&Ac[aoff[t][ks]];
        bq[t][ks] = *(const bf16x8*)&Bc[boff[t][ks]];
      }
    asm volatile("s_waitcnt lgkmcnt(0)" ::: "memory");
    asm volatile("s_barrier" ::: "memory");
    if (i + 2 < nst) STAGE256(i + 2, cur);
    __builtin_amdgcn_s_setprio(1);
#pragma unroll
    for (int mt = 0; mt < 4; ++mt)
#pragma unroll
      for (int nt = 0; nt < 4; ++nt)
#pragma unroll
        for (int ks = 0; ks < 2; ++ks)
          acc[mt][nt] =
              __builtin_amdgcn_mfma_f32_16x16x32_bf16(af[mt][ks], bq[nt][ks], acc[mt][nt], 0, 0, 0);
    __builtin_amdgcn_s_setprio(0);
  }
#undef STAGE256

  const bool isK = KSPLIT && (n0 >= 1024) && (n0 < 2048);
#pragma unroll
  for (int mt = 0; mt < 4; ++mt)
#pragma unroll
    for (int nt = 0; nt < 4; ++nt)
#pragma unroll
      for (int jj = 0; jj < 4; ++jj) {
        int row = m0 + wr * 64 + mt * 16 + lg * 4 + jj;
        int col = n0 + wc * 64 + nt * 16 + lr;
        float v = acc[mt][nt][jj] + bias[col];
        if (OUT_F32) {
          ((float*)Cp)[(size_t)row * N + col] = v;
        } else if (isK) {
          int h = (col - 1024) >> 6, d = col & 63;
          int bq2 = row >> 11, t = row & 2047;
          ((unsigned short*)Kbp)[(size_t)((bq2 * 16 + h) * 2048 + t) * 64 + d] = f2bf(v);
        } else {
          ((unsigned short*)Cp)[(size_t)row * N + col] = f2bf(v);
        }
      }
}

// ---------------- qkv(v part) -> Vt [B,H,D,T] (tiled transpose) ----------------
__global__ __launch_bounds__(256) void vtrans_kernel(const __bf16* __restrict__ qkv,
                                                     __bf16* __restrict__ Vt) {
  __shared__ __align__(16) unsigned short tile[64][72];
  int bh = blockIdx.y, b = bh >> 4, h = bh & 15;
  int t0 = blockIdx.x * 64;
  int tid = threadIdx.x;
#pragma unroll
  for (int p = 0; p < 2; ++p) {
    int idx = p * 256 + tid;
    int r = idx >> 3, c8 = (idx & 7) * 8;
    *(ushort8*)&tile[r][c8] = *(const ushort8*)((const unsigned short*)qkv +
                                                (size_t)(b * 2048 + t0 + r) * 3072 + 2048 +
                                                h * 64 + c8);
  }
  __syncthreads();
#pragma unroll
  for (int p = 0; p < 2; ++p) {
    int idx = p * 256 + tid;
    int d = idx >> 3, c8 = (idx & 7) * 8;
    ushort8 u;
#pragma unroll
    for (int i = 0; i < 8; ++i) u[i] = tile[c8 + i][d];
    *(ushort8*)((unsigned short*)Vt + (size_t)(bh * 64 + d) * 2048 + t0 + c8) = u;
  }
}

// ---------------- flash attention (causal), swapped-QK^T 32x32 (r9 structure) ----------------
// 8 waves x 32 q-rows (QBLK=256), KVBLK=64, double-buffered LDS, 1 barrier/iter.
// r12: complementary block order (CU pairs carry uniform 36 tile-units);
// l-sum via MFMA ones-column (VALU adds -> idle MFMA pipe; shuffle-free epilogue);
// max3-fused row max.
__global__ __launch_bounds__(512) void attn_kernel(const __bf16* __restrict__ qkvp,
                                                   const __bf16* __restrict__ Kg,
                                                   const __bf16* __restrict__ Vt,
                                                   __bf16* __restrict__ yb) {
  __shared__ __align__(16) unsigned short Ks[2][64][72];
  __shared__ __align__(16) unsigned short Vs[2][64][72];
  const int bx = blockIdx.x;
  const int idx = bx >> 6;
  const int qb = (idx < 4) ? (7 - idx) : (idx - 4);  // pairs (i,i+256): 36 units each
  const int bh = bx & 63;
  const int b = bh >> 4, h = bh & 15;
  const int tid = threadIdx.x, wid = tid >> 6, lane = tid & 63;
  const int lq = lane & 31, hi = lane >> 5;
  const unsigned short* qkv = (const unsigned short*)qkvp;
  const unsigned short* Kh = (const unsigned short*)Kg + (size_t)bh * 2048 * 64;
  const unsigned short* Vh = (const unsigned short*)Vt + (size_t)bh * 64 * 2048;
  const int q0w = qb * 256 + wid * 32;
  const int jmax_w = 4 * qb + (wid >> 1);
  const int qrel = (wid & 1) * 32 + lq;
  const int J = 4 * qb + 4;
  const int r = tid >> 3, c8s = (tid & 7) * 8;

  const float qs = 0.125f * 1.44269504f;
  bf16x8 qf[4];
  {
    const unsigned short* Qg = qkv + (size_t)(b * 2048 + q0w + lq) * 3072 + h * 64;
#pragma unroll
    for (int dc = 0; dc < 4; ++dc) {
      ushort8 uq = *(const ushort8*)(Qg + dc * 16 + hi * 8);
      uint4v w;
#pragma unroll
      for (int i = 0; i < 4; ++i) {
        float lo = bf2f(uq[2 * i]) * qs;
        float hh = bf2f(uq[2 * i + 1]) * qs;
        unsigned int up;
        asm("v_cvt_pk_bf16_f32 %0, %1, %2" : "=v"(up) : "v"(lo), "v"(hh));
        w[i] = up;
      }
      qf[dc] = __builtin_bit_cast(bf16x8, w);
    }
  }

  // ones B-fragment for l-sum MFMA
  uint4v ov = {0x3F803F80u, 0x3F803F80u, 0x3F803F80u, 0x3F803F80u};
  const bf16x8 vones = __builtin_bit_cast(bf16x8, ov);

  f32x16 yacc[2] = {};
  f32x16 lacc = {};
  float m_r = -1e30f;

  *(ushort8*)&Ks[0][r][c8s] = *(const ushort8*)(Kh + (size_t)r * 64 + c8s);
  *(ushort8*)&Vs[0][r][c8s] = *(const ushort8*)(Vh + (size_t)r * 2048 + c8s);

  for (int j = 0; j < J; ++j) {
    __syncthreads();
    if (j + 1 < J) {
      int bi = (j + 1) & 1;
      *(ushort8*)&Ks[bi][r][c8s] =
          *(const ushort8*)(Kh + (size_t)((j + 1) * 64 + r) * 64 + c8s);
      *(ushort8*)&Vs[bi][r][c8s] =
          *(const ushort8*)(Vh + (size_t)r * 2048 + (j + 1) * 64 + c8s);
    }
    if (j <= jmax_w) {
      const int cb = j & 1;
      f32x16 sa[2];
#pragma unroll
      for (int kt32 = 0; kt32 < 2; ++kt32) {
        f32x16 s = {};
#pragma unroll
        for (int dc = 0; dc < 4; ++dc) {
          bf16x8 kf = *(const bf16x8*)&Ks[cb][kt32 * 32 + lq][dc * 16 + hi * 8];
          s = __builtin_amdgcn_mfma_f32_32x32x16_bf16(kf, qf[dc], s, 0, 0, 0);
        }
        sa[kt32] = s;
      }
      if (j == jmax_w) {
#pragma unroll
        for (int kt32 = 0; kt32 < 2; ++kt32)
#pragma unroll
          for (int reg = 0; reg < 16; ++reg) {
            int kl = kt32 * 32 + (reg & 3) + 8 * (reg >> 2) + 4 * hi;
            if (kl > qrel) sa[kt32][reg] = -1e30f;
          }
      }
      // row max: fmaxf(fmaxf(p,a),b) fuses to v_max3_f32 -> 16 ops
      float pmax = -1e30f;
#pragma unroll
      for (int kt32 = 0; kt32 < 2; ++kt32)
#pragma unroll
        for (int reg = 0; reg < 16; reg += 2)
          pmax = fmaxf(fmaxf(pmax, sa[kt32][reg]), sa[kt32][reg + 1]);
      pmax = fmaxf(pmax, __shfl_xor(pmax, 32));
      const bool need = __any(pmax > m_r + 8.f) != 0;
      const float mnew = need ? fmaxf(m_r, pmax) : m_r;
      const float alpha = exp2f(m_r - mnew);
      unsigned int u[2][8];
#pragma unroll
      for (int kt32 = 0; kt32 < 2; ++kt32)
#pragma unroll
        for (int rr = 0; rr < 8; ++rr) {
          float p0 = exp2f(sa[kt32][2 * rr] - mnew);
          float p1 = exp2f(sa[kt32][2 * rr + 1] - mnew);
          unsigned int up;
          asm("v_cvt_pk_bf16_f32 %0, %1, %2" : "=v"(up) : "v"(p0), "v"(p1));
          u[kt32][rr] = up;
        }
      m_r = mnew;
      if (need) {
#pragma unroll
        for (int reg = 0; reg < 16; ++reg) {
          int row = (reg & 3) + 8 * (reg >> 2) + 4 * hi;
          float ac = __shfl(alpha, row);
          yacc[0][reg] *= ac;
          yacc[1][reg] *= ac;
          lacc[reg] *= ac;
        }
      }
#pragma unroll
      for (int kt = 0; kt < 4; ++kt) {
        const int kt32 = kt >> 1, off = 4 * (kt & 1);
        unsigned int a0 = u[kt32][off + 0], a2 = u[kt32][off + 2];
        unsigned int a1 = u[kt32][off + 1], a3 = u[kt32][off + 3];
        asm("v_permlane32_swap_b32 %0, %1" : "+v"(a0), "+v"(a2));
        asm("v_permlane32_swap_b32 %0, %1" : "+v"(a1), "+v"(a3));
        uint4v pav = {a0, a1, a2, a3};
        bf16x8 paf = __builtin_bit_cast(bf16x8, pav);
        lacc = __builtin_amdgcn_mfma_f32_32x32x16_bf16(paf, vones, lacc, 0, 0, 0);
#pragma unroll
        for (int dt = 0; dt < 2; ++dt) {
          bf16x8 vf = *(const bf16x8*)&Vs[cb][dt * 32 + lq][kt * 16 + hi * 8];
          yacc[dt] = __builtin_amdgcn_mfma_f32_32x32x16_bf16(paf, vf, yacc[dt], 0, 0, 0);
        }
      }
    }
  }
  // epilogue: lacc[reg] is in yacc's C-layout -> shuffle-free normalize
#pragma unroll
  for (int reg = 0; reg < 16; ++reg) {
    int row = (reg & 3) + 8 * (reg >> 2) + 4 * hi;
    float linv = 1.f / lacc[reg];
    int qg = q0w + row;
#pragma unroll
    for (int dt = 0; dt < 2; ++dt) {
      float v = yacc[dt][reg] * linv;
      ((unsigned short*)yb)[(size_t)(b * 2048 + qg) * 1024 + h * 64 + dt * 32 + lq] = f2bf(v);
    }
  }
}

extern "C" void kernel_launch(void* const* d_in, const int* in_sizes, int n_in,
                              void* d_out, int out_size, void* d_ws, size_t ws_size,
                              hipStream_t stream) {
  const float* x = (const float*)d_in[0];
  const float* W_attn = (const float*)d_in[1];
  const float* b_attn = (const float*)d_in[2];
  const float* W_proj = (const float*)d_in[3];
  const float* b_proj = (const float*)d_in[4];
  float* out = (float*)d_out;
  char* ws = (char*)d_ws;

  size_t off = 0;
  __bf16* WtA = (__bf16*)(ws + off); off += (size_t)3072 * 1024 * 2;
  __bf16* WtP = (__bf16*)(ws + off); off += (size_t)1024 * 1024 * 2;
  __bf16* qkv = (__bf16*)(ws + off); off += (size_t)8192 * 3072 * 2;
  __bf16* Kb  = (__bf16*)(ws + off); off += (size_t)64 * 2048 * 64 * 2;
  __bf16* Vtb = (__bf16*)(ws + off); off += (size_t)64 * 2048 * 64 * 2;
  // xb (x in bf16) dead after GEMM1; yb written only after attn -> alias
  __bf16* xyb = (__bf16*)(ws + off); off += (size_t)8192 * 1024 * 2;
  __bf16* xb = xyb;
  __bf16* yb = xyb;
  (void)ws_size; (void)in_sizes; (void)n_in; (void)out_size;

  f32_to_bf16_kernel<<<4096, 256, 0, stream>>>(x, xb);
  wtrans_kernel<<<dim3(3072 / 32, 1024 / 32), dim3(32, 8), 0, stream>>>(W_attn, WtA, 1024, 3072);
  wtrans_kernel<<<dim3(1024 / 32, 1024 / 32), dim3(32, 8), 0, stream>>>(W_proj, WtP, 1024, 1024);
  // qkv GEMM (r9 256x128 counted-vmcnt); k columns redirected to Kb
  gemm256_kernel<0, 1><<<dim3(24, 32), 512, 0, stream>>>(xb, WtA, b_attn, qkv, Kb, 8192, 3072, 1024);
  vtrans_kernel<<<dim3(32, 64), 256, 0, stream>>>(qkv, Vtb);
  attn_kernel<<<dim3(512), 512, 0, stream>>>(qkv, Kb, Vtb, yb);
  // proj GEMM: 256 blocks = 1/CU
  gemm256_kernel<1, 0><<<dim3(8, 32), 512, 0, stream>>>(yb, WtP, b_proj, out, nullptr, 8192, 1024, 1024);
}